// Round 4
// baseline (1587.227 us; speedup 1.0000x reference)
//
#include <hip/hip_runtime.h>

// Problem constants (from reference setup_inputs)
#define L_DIM 12
#define B_DIM 8
#define H_DIM 12
#define S2    147456              // 384*384
#define M_DIM 32
#define NL 3
#define NH 4
#define HS2   (H_DIM * S2)        // batch stride in attn

// gather design
#define CHB   16                  // st elements per sub-chunk
#define NBLK  512                 // blocks (2 per CU, sequential)
#define SUBS  18                  // sub-chunks per block: 512*18*16 = S2
#define NPMAX 144                 // max unique (l,h) planes
#define SLOT_F 128                // floats per staged plane slot (8 b x 16 sl)

#define PART_FLOATS (NBLK * 256)
#define META_INTS 1024
// mi layout: [0]=np2 [1]=ne ; [8..8+146) pbase ; [160..160+33) moff ;
//            [200..200+384) epack = (slot<<8)|w

typedef const __attribute__((address_space(1))) void GAS;
typedef __attribute__((address_space(3))) void LAS;

// ---------------- setup: per-m gather lists over deduped planes ----------------
__global__ void pfe_setup(const int* __restrict__ lidx, const int* __restrict__ hidx,
                          int* __restrict__ mi)
{
    if (threadIdx.x != 0 || blockIdx.x != 0) return;
    int cl[M_DIM][L_DIM] = {}, ch[M_DIM][H_DIM] = {};
    for (int m = 0; m < M_DIM; ++m) {
        for (int i = 0; i < NL; ++i) cl[m][lidx[m * NL + i]]++;
        for (int j = 0; j < NH; ++j) ch[m][hidx[m * NH + j]]++;
    }
    int slot[L_DIM * H_DIM];
    int np = 0;
    for (int k = 0; k < L_DIM * H_DIM; ++k) {
        const int l = k / H_DIM, h = k % H_DIM;
        bool used = false;
        for (int m = 0; m < M_DIM; ++m)
            if (cl[m][l] && ch[m][h]) { used = true; break; }
        if (used) {
            slot[k] = np;
            mi[8 + np] = (l * (B_DIM * H_DIM) + h) * S2;  // elem offset, b=0
            ++np;
        } else slot[k] = -1;
    }
    const int np2 = (np + 1) & ~1;                 // pad even for pair staging
    for (int p = np; p < np2 + 2; ++p) mi[8 + p] = mi[8 + np - 1];
    mi[0] = np2;
    int ne = 0;
    for (int m = 0; m < M_DIM; ++m) {
        mi[160 + m] = ne;
        for (int k = 0; k < L_DIM * H_DIM; ++k) {
            const int l = k / H_DIM, h = k % H_DIM;
            const int w = cl[m][l] * ch[m][h];
            if (w) { mi[200 + ne] = (slot[k] << 8) | w; ++ne; }
        }
    }
    mi[160 + M_DIM] = ne;
    mi[1] = ne;
}

// stage one sub-chunk (all np2 plane slices) into buf_dst via global_load_lds.
// lane = half*32 + b*4 + q  ->  HW dest = base + lane*16B = slot-half*512B + b*64B + q*16B
__device__ __forceinline__ void stage_sub(
    const float* __restrict__ attn, float* buf_dst,
    const int* s_pbase, int np2, unsigned off, int lane, int wv)
{
    const int half = lane >> 5;
    const unsigned brow = (unsigned)((lane >> 2) & 7) * (unsigned)HS2;
    const unsigned q4 = (unsigned)(lane & 3) * 4u;
    const int npair = np2 >> 1;
    for (int pr = wv; pr < npair; pr += 4) {
        const int pb = s_pbase[2 * pr + half];
        const float* src = attn + ((unsigned)pb + brow + off + q4);
        __builtin_amdgcn_global_load_lds((GAS*)src, (LAS*)(buf_dst + pr * (2 * SLOT_F)),
                                         16, 0, 0);
    }
}

// ---------------- main: stream planes once, register-gather per m ----------------
__global__ __launch_bounds__(256, 1) void pfe_gather(
    const float* __restrict__ attn, const float* __restrict__ refs,
    const int* __restrict__ mi, float* __restrict__ part)
{
    __shared__ float buf[2][NPMAX * SLOT_F];   // 2 x 72 KB
    __shared__ int s_pbase[NPMAX + 2];
    __shared__ int s_moff[M_DIM + 1];
    __shared__ int s_epack[M_DIM * NL * NH];

    const int t = threadIdx.x;
    const int np2 = mi[0];
    const int ne  = mi[1];
    for (int i = t; i < np2 + 2; i += 256) s_pbase[i] = mi[8 + i];
    for (int i = t; i < M_DIM + 1; i += 256) s_moff[i] = mi[160 + i];
    for (int i = t; i < ne; i += 256) s_epack[i] = mi[200 + i];
    __syncthreads();

    const int lane = t & 63, wv = t >> 6;
    const unsigned off0 = (unsigned)blockIdx.x * (SUBS * CHB);

    stage_sub(attn, buf[0], s_pbase, np2, off0, lane, wv);

    // compute mapping: g = half of m-range, bb = batch, sl = st within sub-chunk
    const int g  = t >> 7;
    const int bb = (t >> 4) & 7;
    const int sl = t & 15;
    const int m0 = g * 16;
    // stats mapping: (m = sm + 16*k2, ssl)
    const int sm  = t >> 4;
    const int ssl = t & 15;

    float zsq[2][B_DIM];
#pragma unroll
    for (int k = 0; k < 2; ++k)
#pragma unroll
        for (int b = 0; b < B_DIM; ++b) zsq[k][b] = 0.f;

    int cur = 0;
    for (int it = 0; it < SUBS; ++it) {
        const unsigned off = off0 + (unsigned)it * CHB;
        __syncthreads();   // buf[cur] staged (drains this wave's loads + barrier)
        if (it + 1 < SUBS)
            stage_sub(attn, buf[cur ^ 1], s_pbase, np2, off + CHB, lane, wv);

        float* base = buf[cur];
        const float* bp = base + bb * CHB + sl;
        float acc[16];
#pragma unroll
        for (int k = 0; k < 16; ++k) {
            const int m = m0 + k;
            const int e0 = s_moff[m], e1 = s_moff[m + 1];
            float a = 0.f;
            for (int e = e0; e < e1; ++e) {
                const int v = s_epack[e];          // broadcast read
                const float w = (float)(v & 255);
                a = fmaf(w, bp[(v >> 8) * SLOT_F], a);
            }
            acc[k] = a;
        }
        __syncthreads();   // all reads of buf[cur] done
        const float c12 = 1.0f / 12.0f;
#pragma unroll
        for (int k = 0; k < 16; ++k)
            base[(m0 + k) * SLOT_F + bb * CHB + sl] = acc[k] * c12;
        __syncthreads();   // pm ready

#pragma unroll
        for (int k2 = 0; k2 < 2; ++k2) {
            const int m = sm + 16 * k2;
            float x[B_DIM], mu = 0.f;
#pragma unroll
            for (int b = 0; b < B_DIM; ++b) {
                x[b] = base[m * SLOT_F + b * CHB + ssl];
                mu += x[b];
            }
            mu *= 0.125f;
            float ss = 0.f;
#pragma unroll
            for (int b = 0; b < B_DIM; ++b) {
                const float d = x[b] - mu;
                ss = fmaf(d, d, ss);
            }
            const float inv = 1.0f / fmaxf(sqrtf(ss * (1.0f / 7.0f)), 1e-8f);
            const float rv = refs[(size_t)m * S2 + off + ssl];
#pragma unroll
            for (int b = 0; b < B_DIM; ++b) {
                const float z = (x[b] - rv) * inv;
                zsq[k2][b] = fmaf(z, z, zsq[k2][b]);
            }
        }
        cur ^= 1;
    }

    // reduce zsq over ssl (16-lane groups, butterfly)
#pragma unroll
    for (int k2 = 0; k2 < 2; ++k2)
#pragma unroll
        for (int b = 0; b < B_DIM; ++b) {
            float v = zsq[k2][b];
            v += __shfl_xor(v, 1);
            v += __shfl_xor(v, 2);
            v += __shfl_xor(v, 4);
            v += __shfl_xor(v, 8);
            zsq[k2][b] = v;
        }
    if ((t & 15) == 0) {
#pragma unroll
        for (int k2 = 0; k2 < 2; ++k2)
#pragma unroll
            for (int b = 0; b < B_DIM; ++b)
                part[blockIdx.x * 256 + (sm + 16 * k2) * B_DIM + b] = zsq[k2][b];
    }
}

// ---------------- deterministic final reduction ----------------
__global__ __launch_bounds__(256) void pfe_final(
    const float* __restrict__ part, float* __restrict__ out)
{
    const int t = threadIdx.x;          // t = m*8 + b
    float s = 0.f;
    for (int blk = 0; blk < NBLK; ++blk) s += part[blk * 256 + t];
    out[(t & 7) * M_DIM + (t >> 3)] = s * (1.0f / (float)S2);
}

// ---------------- fallback path (tiny ws): per-(m,chunk) atomic ----------------
__global__ void pfe_zero(float* __restrict__ out) {
    if (threadIdx.x < M_DIM * B_DIM) out[threadIdx.x] = 0.f;
}

#define FCH 512
#define FNCH (S2 / FCH)
__global__ __launch_bounds__(128) void pfe_fallback(
    const float* __restrict__ attn, const float* __restrict__ refs,
    const int* __restrict__ lidx, const int* __restrict__ hidx,
    float* __restrict__ out)
{
    const int p = blockIdx.x;
    const int m = p & (M_DIM - 1);
    const int chunk = p >> 5;
    const int tid = threadIdx.x;
    const unsigned st = (unsigned)chunk * FCH + (unsigned)tid * 4;

    __shared__ int   s_mk[NL * NH];
    __shared__ float s_mw[NL * NH];
    __shared__ int   s_nm;
    __shared__ float s_red[2 * B_DIM];

    if (tid == 0) {
        int keys[NL * NH];
        for (int i = 0; i < NL; ++i) {
            const int l = lidx[m * NL + i];
            for (int j = 0; j < NH; ++j) keys[i * NH + j] = l * 16 + hidx[m * NH + j];
        }
        for (int i = 1; i < NL * NH; ++i) {
            const int k = keys[i]; int j = i - 1;
            for (; j >= 0 && keys[j] > k; --j) keys[j + 1] = keys[j];
            keys[j + 1] = k;
        }
        int nm = 0;
        for (int i = 0; i < NL * NH; ++i) {
            if (nm > 0 && s_mk[nm - 1] == keys[i]) s_mw[nm - 1] += 1.0f;
            else { s_mk[nm] = keys[i]; s_mw[nm] = 1.0f; ++nm; }
        }
        s_nm = nm;
    }
    __syncthreads();

    const float4 r = *reinterpret_cast<const float4*>(refs + (unsigned)m * (unsigned)S2 + st);
    float4 acc[B_DIM];
    for (int bb = 0; bb < B_DIM; ++bb) acc[bb] = make_float4(0.f, 0.f, 0.f, 0.f);
    const int nm = s_nm;
    for (int e = 0; e < nm; ++e) {
        const int k = s_mk[e]; const float w = s_mw[e];
        const int l = k >> 4, h = k & 15;
        const unsigned base = (unsigned)(l * (B_DIM * H_DIM) + h) * (unsigned)S2 + st;
        for (int bb = 0; bb < B_DIM; ++bb) {
            const float4 v = *reinterpret_cast<const float4*>(
                attn + base + (unsigned)bb * (unsigned)HS2);
            acc[bb].x = fmaf(w, v.x, acc[bb].x); acc[bb].y = fmaf(w, v.y, acc[bb].y);
            acc[bb].z = fmaf(w, v.z, acc[bb].z); acc[bb].w = fmaf(w, v.w, acc[bb].w);
        }
    }
    const float c12 = 1.0f / 12.0f;
    float4 pmv[B_DIM];
    for (int bb = 0; bb < B_DIM; ++bb) {
        pmv[bb].x = acc[bb].x * c12; pmv[bb].y = acc[bb].y * c12;
        pmv[bb].z = acc[bb].z * c12; pmv[bb].w = acc[bb].w * c12;
    }
    float4 mu = make_float4(0.f, 0.f, 0.f, 0.f);
    for (int bb = 0; bb < B_DIM; ++bb) {
        mu.x += pmv[bb].x; mu.y += pmv[bb].y; mu.z += pmv[bb].z; mu.w += pmv[bb].w;
    }
    mu.x *= 0.125f; mu.y *= 0.125f; mu.z *= 0.125f; mu.w *= 0.125f;
    float4 ss = make_float4(0.f, 0.f, 0.f, 0.f);
    for (int bb = 0; bb < B_DIM; ++bb) {
        const float dx = pmv[bb].x - mu.x, dy = pmv[bb].y - mu.y,
                    dz = pmv[bb].z - mu.z, dw = pmv[bb].w - mu.w;
        ss.x += dx * dx; ss.y += dy * dy; ss.z += dz * dz; ss.w += dw * dw;
    }
    const float c7 = 1.0f / 7.0f;
    float4 inv;
    inv.x = 1.0f / fmaxf(sqrtf(ss.x * c7), 1e-8f);
    inv.y = 1.0f / fmaxf(sqrtf(ss.y * c7), 1e-8f);
    inv.z = 1.0f / fmaxf(sqrtf(ss.z * c7), 1e-8f);
    inv.w = 1.0f / fmaxf(sqrtf(ss.w * c7), 1e-8f);
    float s[B_DIM];
    for (int bb = 0; bb < B_DIM; ++bb) {
        const float zx = (pmv[bb].x - r.x) * inv.x;
        const float zy = (pmv[bb].y - r.y) * inv.y;
        const float zz = (pmv[bb].z - r.z) * inv.z;
        const float zw = (pmv[bb].w - r.w) * inv.w;
        s[bb] = zx * zx + zy * zy + zz * zz + zw * zw;
    }
    for (int bb = 0; bb < B_DIM; ++bb) {
        float v = s[bb];
        for (int off = 32; off > 0; off >>= 1) v += __shfl_down(v, off);
        s[bb] = v;
    }
    const int lane = tid & 63, wave = tid >> 6;
    if (lane == 0) for (int bb = 0; bb < B_DIM; ++bb) s_red[wave * B_DIM + bb] = s[bb];
    __syncthreads();
    if (tid < B_DIM) {
        const float tot = (s_red[tid] + s_red[B_DIM + tid]) * (1.0f / (float)S2);
        atomicAdd(&out[tid * M_DIM + m], tot);
    }
}

extern "C" void kernel_launch(void* const* d_in, const int* in_sizes, int n_in,
                              void* d_out, int out_size, void* d_ws, size_t ws_size,
                              hipStream_t stream) {
    const float* attn = (const float*)d_in[0];
    const float* refs = (const float*)d_in[1];
    const int*   lidx = (const int*)d_in[2];
    const int*   hidx = (const int*)d_in[3];
    float* out = (float*)d_out;

    const size_t ws_needed = (size_t)(PART_FLOATS + META_INTS) * sizeof(float);

    if (ws_size >= ws_needed) {
        float* part = (float*)d_ws;
        int*   mi   = (int*)(part + PART_FLOATS);
        pfe_setup<<<1, 64, 0, stream>>>(lidx, hidx, mi);
        pfe_gather<<<NBLK, 256, 0, stream>>>(attn, refs, mi, part);
        pfe_final<<<1, 256, 0, stream>>>(part, out);
    } else {
        pfe_zero<<<1, 256, 0, stream>>>(out);
        pfe_fallback<<<FNCH * M_DIM, 128, 0, stream>>>(attn, refs, lidx, hidx, out);
    }
}

// Round 5
// 208.727 us; speedup vs baseline: 7.6043x; 7.6043x over previous
//
#include <hip/hip_runtime.h>

// Problem constants (from reference setup_inputs)
#define L_DIM 12
#define B_DIM 8
#define H_DIM 12
#define S2    147456              // 384*384
#define M_DIM 32
#define NL 3
#define NH 4
#define HS2   (H_DIM * S2)        // batch stride in attn elements

// gather design
#define CHB   16                  // st elements per sub-chunk
#define NBLK  256                 // one block per CU
#define SUBS  36                  // 256*36*16 = S2
#define NPMAX 146                 // plane slots (<=144 used + pad)

#define PART_FLOATS (NBLK * 256)
#define META_INTS 256
// mi layout: [0]=np2 ; [8..8+np2+2) plane elem offsets ; [160..160+96) packed
//            per-m slot lists: 3 ints/m, word c packs slots of (l_c, h_0..3)

typedef const __attribute__((address_space(1))) void GAS;
typedef __attribute__((address_space(3))) void LAS;

// ---------------- setup: parallel, LDS-only ----------------
__global__ __launch_bounds__(256) void pfe_setup(
    const int* __restrict__ lidx, const int* __restrict__ hidx, int* __restrict__ mi)
{
    __shared__ unsigned char s_cl[M_DIM][L_DIM];
    __shared__ unsigned char s_ch[M_DIM][H_DIM];
    __shared__ int s_used[L_DIM * H_DIM];
    __shared__ int s_slot[L_DIM * H_DIM];
    const int t = threadIdx.x;
    if (t < M_DIM) {
        for (int l = 0; l < L_DIM; ++l) s_cl[t][l] = 0;
        for (int h = 0; h < H_DIM; ++h) s_ch[t][h] = 0;
        for (int i = 0; i < NL; ++i) s_cl[t][lidx[t * NL + i]]++;
        for (int j = 0; j < NH; ++j) s_ch[t][hidx[t * NH + j]]++;
    }
    __syncthreads();
    if (t < L_DIM * H_DIM) {
        const int l = t / H_DIM, h = t % H_DIM;
        int u = 0;
        for (int m = 0; m < M_DIM; ++m) u |= (s_cl[m][l] && s_ch[m][h]) ? 1 : 0;
        s_used[t] = u;
    }
    __syncthreads();
    if (t == 0) {
        int np = 0, lastb = 0;
        for (int k = 0; k < L_DIM * H_DIM; ++k) {
            if (s_used[k]) {
                s_slot[k] = np;
                lastb = ((k / H_DIM) * (B_DIM * H_DIM) + (k % H_DIM)) * S2;
                mi[8 + np] = lastb;
                ++np;
            } else s_slot[k] = -1;
        }
        const int np2 = (np + 1) & ~1;
        for (int p = np; p < np2 + 2; ++p) mi[8 + p] = lastb;
        mi[0] = np2;
    }
    __syncthreads();
    if (t < M_DIM) {
        for (int c = 0; c < NL; ++c) {
            const int l = lidx[t * NL + c];
            int w = 0;
            for (int q = 0; q < NH; ++q)
                w |= s_slot[l * H_DIM + hidx[t * NH + q]] << (8 * q);
            mi[160 + t * 3 + c] = w;
        }
    }
}

// stage one sub-chunk (np2 plane slices x 8 b x 16 sl) via global_load_lds.
// lane = half*32 + b*4 + q  ->  HW dest = base + lane*16B = slot-half*512B + b*64B + q*16B
__device__ __forceinline__ void stage_sub(
    const float* __restrict__ attn, float* buf_dst,
    const int* s_pbase, int np2, unsigned off, int lane, int wv)
{
    const int half = lane >> 5;
    const unsigned brow = (unsigned)((lane >> 2) & 7) * (unsigned)HS2;
    const unsigned q4 = (unsigned)(lane & 3) * 4u;
    const int npair = np2 >> 1;
    for (int pr = wv; pr < npair; pr += 8) {
        const int pb = s_pbase[2 * pr + half];
        const float* src = attn + ((unsigned)pb + brow + off + q4);
        __builtin_amdgcn_global_load_lds((GAS*)src, (LAS*)(buf_dst + pr * 256), 16, 0, 0);
    }
}

// ---------------- main: stream planes once, register-gather, in-wave stats ----
// 512 threads: t = [wave mg:3][bb:3][slp:3]; each thread: m in {mg+8k}, k=0..3,
// batch bb, st pair sl = slp*2.
__global__ __launch_bounds__(512, 1) void pfe_gather(
    const float* __restrict__ attn, const float* __restrict__ refs,
    const int* __restrict__ mi, float* __restrict__ part)
{
    __shared__ float buf[2][NPMAX * 128];   // 149.5 KB
    __shared__ int s_pbase[NPMAX + 2];
    __shared__ int s_mpack[M_DIM * 3];

    const int t = threadIdx.x;
    const int np2 = mi[0];
    for (int i = t; i < np2 + 2; i += 512) s_pbase[i] = mi[8 + i];
    for (int i = t; i < M_DIM * 3; i += 512) s_mpack[i] = mi[160 + i];
    __syncthreads();

    const int lane = t & 63, wv = t >> 6;
    const int mg = wv;                 // wave-uniform m-group
    const int bb = (t >> 3) & 7;
    const int slp = t & 7;

    int pk[12];
#pragma unroll
    for (int k = 0; k < 4; ++k)
#pragma unroll
        for (int c = 0; c < 3; ++c)
            pk[k * 3 + c] = s_mpack[(mg + 8 * k) * 3 + c];

    const unsigned off0 = (unsigned)blockIdx.x * (SUBS * CHB);
    stage_sub(attn, buf[0], s_pbase, np2, off0, lane, wv);

    const int myoff = bb * CHB + slp * 2;   // float offset within slot
    float zsq[4] = {0.f, 0.f, 0.f, 0.f};
    const float c12 = 1.0f / 12.0f;

    int cur = 0;
    for (int it = 0; it < SUBS; ++it) {
        __syncthreads();   // buf[cur] staged (drains loads + barrier)
        if (it + 1 < SUBS)
            stage_sub(attn, buf[cur ^ 1], s_pbase, np2,
                      off0 + (unsigned)(it + 1) * CHB, lane, wv);

        const float* bp = buf[cur] + myoff;
        float ax[4], ay[4];
#pragma unroll
        for (int k = 0; k < 4; ++k) {
            float sx = 0.f, sy = 0.f;
#pragma unroll
            for (int j = 0; j < NL * NH; ++j) {
                const int e = k * 12 + j;
                const int slot = (pk[e >> 2] >> ((e & 3) * 8)) & 255;
                const float2 v = *reinterpret_cast<const float2*>(bp + slot * 128);
                sx += v.x; sy += v.y;
            }
            ax[k] = sx * c12; ay[k] = sy * c12;
        }

        // in-wave stats: sum over bb = lane bits 3..5 (xor 8,16,32)
        const unsigned off = off0 + (unsigned)it * CHB;
#pragma unroll
        for (int k = 0; k < 4; ++k) {
            const int m = mg + 8 * k;
            float mx = ax[k], my = ay[k];
            mx += __shfl_xor(mx, 8);  my += __shfl_xor(my, 8);
            mx += __shfl_xor(mx, 16); my += __shfl_xor(my, 16);
            mx += __shfl_xor(mx, 32); my += __shfl_xor(my, 32);
            mx *= 0.125f; my *= 0.125f;
            const float dx = ax[k] - mx, dy = ay[k] - my;
            float sx = dx * dx, sy = dy * dy;
            sx += __shfl_xor(sx, 8);  sy += __shfl_xor(sy, 8);
            sx += __shfl_xor(sx, 16); sy += __shfl_xor(sy, 16);
            sx += __shfl_xor(sx, 32); sy += __shfl_xor(sy, 32);
            const float invx = 1.0f / fmaxf(sqrtf(sx * (1.0f / 7.0f)), 1e-8f);
            const float invy = 1.0f / fmaxf(sqrtf(sy * (1.0f / 7.0f)), 1e-8f);
            const float2 rv = *reinterpret_cast<const float2*>(
                refs + (size_t)m * S2 + off + slp * 2);
            const float zx = (ax[k] - rv.x) * invx;
            const float zy = (ay[k] - rv.y) * invy;
            zsq[k] = fmaf(zx, zx, fmaf(zy, zy, zsq[k]));
        }
        cur ^= 1;
    }

    // reduce zsq over slp (lane bits 0..2), writer slp==0
#pragma unroll
    for (int k = 0; k < 4; ++k) {
        float v = zsq[k];
        v += __shfl_xor(v, 1);
        v += __shfl_xor(v, 2);
        v += __shfl_xor(v, 4);
        zsq[k] = v;
    }
    if ((t & 7) == 0) {
#pragma unroll
        for (int k = 0; k < 4; ++k)
            part[blockIdx.x * 256 + (mg + 8 * k) * B_DIM + bb] = zsq[k];
    }
}

// ---------------- deterministic final reduction ----------------
__global__ __launch_bounds__(256) void pfe_final(
    const float* __restrict__ part, float* __restrict__ out)
{
    const int t = threadIdx.x;          // t = m*8 + b
    float s = 0.f;
    for (int blk = 0; blk < NBLK; ++blk) s += part[blk * 256 + t];
    out[(t & 7) * M_DIM + (t >> 3)] = s * (1.0f / (float)S2);
}

// ---------------- fallback path (tiny ws): per-(m,chunk) atomic ----------------
__global__ void pfe_zero(float* __restrict__ out) {
    if (threadIdx.x < M_DIM * B_DIM) out[threadIdx.x] = 0.f;
}

#define FCH 512
#define FNCH (S2 / FCH)
__global__ __launch_bounds__(128) void pfe_fallback(
    const float* __restrict__ attn, const float* __restrict__ refs,
    const int* __restrict__ lidx, const int* __restrict__ hidx,
    float* __restrict__ out)
{
    const int p = blockIdx.x;
    const int m = p & (M_DIM - 1);
    const int chunk = p >> 5;
    const int tid = threadIdx.x;
    const unsigned st = (unsigned)chunk * FCH + (unsigned)tid * 4;

    __shared__ int   s_mk[NL * NH];
    __shared__ float s_mw[NL * NH];
    __shared__ int   s_nm;
    __shared__ float s_red[2 * B_DIM];

    if (tid == 0) {
        int keys[NL * NH];
        for (int i = 0; i < NL; ++i) {
            const int l = lidx[m * NL + i];
            for (int j = 0; j < NH; ++j) keys[i * NH + j] = l * 16 + hidx[m * NH + j];
        }
        for (int i = 1; i < NL * NH; ++i) {
            const int k = keys[i]; int j = i - 1;
            for (; j >= 0 && keys[j] > k; --j) keys[j + 1] = keys[j];
            keys[j + 1] = k;
        }
        int nm = 0;
        for (int i = 0; i < NL * NH; ++i) {
            if (nm > 0 && s_mk[nm - 1] == keys[i]) s_mw[nm - 1] += 1.0f;
            else { s_mk[nm] = keys[i]; s_mw[nm] = 1.0f; ++nm; }
        }
        s_nm = nm;
    }
    __syncthreads();

    const float4 r = *reinterpret_cast<const float4*>(refs + (unsigned)m * (unsigned)S2 + st);
    float4 acc[B_DIM];
    for (int bb = 0; bb < B_DIM; ++bb) acc[bb] = make_float4(0.f, 0.f, 0.f, 0.f);
    const int nm = s_nm;
    for (int e = 0; e < nm; ++e) {
        const int k = s_mk[e]; const float w = s_mw[e];
        const int l = k >> 4, h = k & 15;
        const unsigned base = (unsigned)(l * (B_DIM * H_DIM) + h) * (unsigned)S2 + st;
        for (int bb = 0; bb < B_DIM; ++bb) {
            const float4 v = *reinterpret_cast<const float4*>(
                attn + base + (unsigned)bb * (unsigned)HS2);
            acc[bb].x = fmaf(w, v.x, acc[bb].x); acc[bb].y = fmaf(w, v.y, acc[bb].y);
            acc[bb].z = fmaf(w, v.z, acc[bb].z); acc[bb].w = fmaf(w, v.w, acc[bb].w);
        }
    }
    const float c12 = 1.0f / 12.0f;
    float4 pmv[B_DIM];
    for (int bb = 0; bb < B_DIM; ++bb) {
        pmv[bb].x = acc[bb].x * c12; pmv[bb].y = acc[bb].y * c12;
        pmv[bb].z = acc[bb].z * c12; pmv[bb].w = acc[bb].w * c12;
    }
    float4 mu = make_float4(0.f, 0.f, 0.f, 0.f);
    for (int bb = 0; bb < B_DIM; ++bb) {
        mu.x += pmv[bb].x; mu.y += pmv[bb].y; mu.z += pmv[bb].z; mu.w += pmv[bb].w;
    }
    mu.x *= 0.125f; mu.y *= 0.125f; mu.z *= 0.125f; mu.w *= 0.125f;
    float4 ss = make_float4(0.f, 0.f, 0.f, 0.f);
    for (int bb = 0; bb < B_DIM; ++bb) {
        const float dx = pmv[bb].x - mu.x, dy = pmv[bb].y - mu.y,
                    dz = pmv[bb].z - mu.z, dw = pmv[bb].w - mu.w;
        ss.x += dx * dx; ss.y += dy * dy; ss.z += dz * dz; ss.w += dw * dw;
    }
    const float c7 = 1.0f / 7.0f;
    float4 inv;
    inv.x = 1.0f / fmaxf(sqrtf(ss.x * c7), 1e-8f);
    inv.y = 1.0f / fmaxf(sqrtf(ss.y * c7), 1e-8f);
    inv.z = 1.0f / fmaxf(sqrtf(ss.z * c7), 1e-8f);
    inv.w = 1.0f / fmaxf(sqrtf(ss.w * c7), 1e-8f);
    float s[B_DIM];
    for (int bb = 0; bb < B_DIM; ++bb) {
        const float zx = (pmv[bb].x - r.x) * inv.x;
        const float zy = (pmv[bb].y - r.y) * inv.y;
        const float zz = (pmv[bb].z - r.z) * inv.z;
        const float zw = (pmv[bb].w - r.w) * inv.w;
        s[bb] = zx * zx + zy * zy + zz * zz + zw * zw;
    }
    for (int bb = 0; bb < B_DIM; ++bb) {
        float v = s[bb];
        for (int off = 32; off > 0; off >>= 1) v += __shfl_down(v, off);
        s[bb] = v;
    }
    const int lane = tid & 63, wave = tid >> 6;
    if (lane == 0) for (int bb = 0; bb < B_DIM; ++bb) s_red[wave * B_DIM + bb] = s[bb];
    __syncthreads();
    if (tid < B_DIM) {
        const float tot = (s_red[tid] + s_red[B_DIM + tid]) * (1.0f / (float)S2);
        atomicAdd(&out[tid * M_DIM + m], tot);
    }
}

extern "C" void kernel_launch(void* const* d_in, const int* in_sizes, int n_in,
                              void* d_out, int out_size, void* d_ws, size_t ws_size,
                              hipStream_t stream) {
    const float* attn = (const float*)d_in[0];
    const float* refs = (const float*)d_in[1];
    const int*   lidx = (const int*)d_in[2];
    const int*   hidx = (const int*)d_in[3];
    float* out = (float*)d_out;

    const size_t ws_needed = (size_t)(PART_FLOATS + META_INTS) * sizeof(float);

    if (ws_size >= ws_needed) {
        float* part = (float*)d_ws;
        int*   mi   = (int*)(part + PART_FLOATS);
        pfe_setup<<<1, 256, 0, stream>>>(lidx, hidx, mi);
        pfe_gather<<<NBLK, 512, 0, stream>>>(attn, refs, mi, part);
        pfe_final<<<1, 256, 0, stream>>>(part, out);
    } else {
        pfe_zero<<<1, 256, 0, stream>>>(out);
        pfe_fallback<<<FNCH * M_DIM, 128, 0, stream>>>(attn, refs, lidx, hidx, out);
    }
}